// Round 7
// baseline (809.036 us; speedup 1.0000x reference)
//
#include <hip/hip_runtime.h>

// ---------- types ----------
typedef __bf16 bf16_t;
typedef bf16_t bf16x8 __attribute__((ext_vector_type(8)));
typedef bf16_t bf16x4 __attribute__((ext_vector_type(4)));
typedef bf16_t bf16x2 __attribute__((ext_vector_type(2)));
typedef float f32x4 __attribute__((ext_vector_type(4)));
typedef float f32x16 __attribute__((ext_vector_type(16)));
typedef unsigned int uint32x4 __attribute__((ext_vector_type(4)));

// ---------- helpers ----------
__device__ __forceinline__ ushort f2bu(float f) {  // fp32 -> bf16 bits (RNE)
  unsigned u = __float_as_uint(f);
  unsigned r = (u + 0x7fffu + ((u >> 16) & 1u)) >> 16;
  return (ushort)r;
}
__device__ __forceinline__ float b2f(ushort u) {
  return __uint_as_float(((unsigned)u) << 16);
}

typedef const __attribute__((address_space(1))) unsigned int* gas_ptr;
typedef __attribute__((address_space(3))) unsigned int* las_ptr;
__device__ __forceinline__ void g2l16(const void* g, void* l) {
  // async global->LDS, 16B per lane; LDS dest = wave-uniform base + lane*16
  __builtin_amdgcn_global_load_lds((gas_ptr)g, (las_ptr)l, 16, 0, 0);
}

// ---------- pack x -> bf16 + mask (mask premultiplied by log2(e)) ----------
__global__ __launch_bounds__(256) void pack_x(const float* __restrict__ x,
                                              ushort* __restrict__ xb,
                                              float* __restrict__ maskv) {
  int row = blockIdx.x;
  int tid = threadIdx.x;
  const float4 v = ((const float4*)(x + (size_t)row * 1024))[tid];
  ushort4 o;
  o.x = f2bu(v.x); o.y = f2bu(v.y); o.z = f2bu(v.z); o.w = f2bu(v.w);
  ((ushort4*)(xb + (size_t)row * 1024))[tid] = o;
  float s = v.x + v.y + v.z + v.w;
#pragma unroll
  for (int m = 1; m < 64; m <<= 1) s += __shfl_xor(s, m);
  __shared__ float wsum[4];
  if ((tid & 63) == 0) wsum[tid >> 6] = s;
  __syncthreads();
  if (tid == 0)
    maskv[row] = ((wsum[0] + wsum[1] + wsum[2] + wsum[3]) != 0.f)
                     ? 1.4426950408889634f : 0.f;
}

// ---------- pack weight: transpose + cast (wt[n][k] = w[k][n]) ----------
__global__ __launch_bounds__(1024) void pack_w(const float* __restrict__ w,
                                               ushort* __restrict__ wt) {
  __shared__ float t[32][33];
  int n0 = blockIdx.x * 32, k0 = blockIdx.y * 32;
  int tx = threadIdx.x, ty = threadIdx.y;
  t[ty][tx] = w[(size_t)(k0 + ty) * 1024 + n0 + tx];
  __syncthreads();
  wt[(size_t)(n0 + ty) * 1024 + k0 + tx] = f2bu(t[tx][ty]);
}

// ---------- fused QKV GEMM: [8192,1024] @ [3072,1024]^T, RoPE in epilogue --
// BT rows 0..1023 = wq^T, 1024..2047 = wk^T, 2048..3071 = wv^T.
// Q out (x SCL, roped) -> [b][h][l][d]; K out (roped) -> [b][h][l][d];
// V out -> [b][h][d][l] (transposed).
__global__ __launch_bounds__(256) void qkv_gemm(const ushort* __restrict__ A,
                                                const ushort* __restrict__ BT,
                                                ushort* __restrict__ Qo,
                                                ushort* __restrict__ Ko,
                                                ushort* __restrict__ VTo) {
  __shared__ ushort lA[128 * 64];
  __shared__ ushort lB[128 * 64];
  const int tid = threadIdx.x;
  const int wave = tid >> 6, lane = tid & 63;
  const int lr = lane & 15, lk = lane >> 4;
  // bijective XCD-chunked swizzle: 1536 blocks, 192/XCD (3 B-panels resident)
  const int f = blockIdx.x;
  const int wgid = (f & 7) * 192 + (f >> 3);
  const int bm = (wgid & 63) * 128, bn = (wgid >> 6) * 128;
  const int wr = (wave >> 1) * 64, wc = (wave & 1) * 64;
  f32x4 acc[4][4] = {};
  for (int kt = 0; kt < 1024; kt += 64) {
#pragma unroll
    for (int t = 0; t < 4; ++t) {
      int e = (t * 256 + tid) * 8;
      int row = e >> 6, col = e & 63;
      g2l16(A + (size_t)(bm + row) * 1024 + kt + col, lA + e);
      g2l16(BT + (size_t)(bn + row) * 1024 + kt + col, lB + e);
    }
    __syncthreads();
#pragma unroll
    for (int ks = 0; ks < 2; ++ks) {
      bf16x8 af[4], bfr[4];
#pragma unroll
      for (int i = 0; i < 4; ++i)
        af[i] = *(const bf16x8*)(lA + (wr + i * 16 + lr) * 64 + ks * 32 + lk * 8);
#pragma unroll
      for (int j = 0; j < 4; ++j)
        bfr[j] = *(const bf16x8*)(lB + (wc + j * 16 + lr) * 64 + ks * 32 + lk * 8);
#pragma unroll
      for (int i = 0; i < 4; ++i)
#pragma unroll
        for (int j = 0; j < 4; ++j)
          acc[i][j] = __builtin_amdgcn_mfma_f32_16x16x32_bf16(af[i], bfr[j],
                                                              acc[i][j], 0, 0, 0);
    }
    __syncthreads();
  }
  // epilogue; C/D map: col = lane&15 (n), row = (lane>>4)*4 + reg (m)
  const int which = bn >> 10;  // 0=Q 1=K 2=V, uniform per block
  const float SCL = 0.18033688011112042f;  // 0.125 * log2(e)
  const float cc = 0.41524101186092029f;   // log2(10000)/32
  if (which < 2) {
    ushort* dst = which ? Ko : Qo;
    float invf[4];
#pragma unroll
    for (int j = 0; j < 4; ++j) {
      int d = (wc + j * 16 + lr) & 63;
      invf[j] = exp2f(-cc * (float)(d >> 1));
    }
#pragma unroll
    for (int i = 0; i < 4; ++i)
#pragma unroll
      for (int r = 0; r < 4; ++r) {
        int m = bm + wr + i * 16 + lk * 4 + r;
        int b = m >> 11, l = m & 2047;
#pragma unroll
        for (int j = 0; j < 4; ++j) {
          int c10 = (bn + wc + j * 16 + lr) & 1023;
          int h = c10 >> 6, d = c10 & 63;
          float v = acc[i][j][r];
          float pv = __shfl_xor(v, 1);  // partner element of the rope pair
          float sv, cv;
          sincosf((float)l * invf[j], &sv, &cv);
          float out = (d & 1) ? (pv * sv + v * cv)   // odd: x1*sin + x2*cos
                              : (v * cv - pv * sv);  // even: x1*cos - x2*sin
          if (which == 0) out *= SCL;
          dst[(((size_t)b * 16 + h) * 2048 + l) * 64 + d] = f2bu(out);
        }
      }
  } else {
#pragma unroll
    for (int i = 0; i < 4; ++i)
#pragma unroll
      for (int r = 0; r < 4; ++r) {
        int m = bm + wr + i * 16 + lk * 4 + r;
        int b = m >> 11, l = m & 2047;
#pragma unroll
        for (int j = 0; j < 4; ++j) {
          int c10 = (bn + wc + j * 16 + lr) & 1023;
          int h = c10 >> 6, d = c10 & 63;
          VTo[(((size_t)b * 16 + h) * 64 + d) * 2048 + l] = f2bu(acc[i][j][r]);
        }
      }
  }
}

// ---------- WO GEMM: fp32 out row-major ----------
__global__ __launch_bounds__(256) void wo_gemm(const ushort* __restrict__ A,
                                               const ushort* __restrict__ BT,
                                               float* __restrict__ C) {
  __shared__ ushort lA[128 * 64];
  __shared__ ushort lB[128 * 64];
  const int tid = threadIdx.x;
  const int wave = tid >> 6, lane = tid & 63;
  const int lr = lane & 15, lk = lane >> 4;
  const int f = blockIdx.x;
  const int wgid = (f & 7) * 64 + (f >> 3);   // 512 blocks, bijective
  const int bm = (wgid & 63) * 128, bn = (wgid >> 6) * 128;
  const int wr = (wave >> 1) * 64, wc = (wave & 1) * 64;
  f32x4 acc[4][4] = {};
  for (int kt = 0; kt < 1024; kt += 64) {
#pragma unroll
    for (int t = 0; t < 4; ++t) {
      int e = (t * 256 + tid) * 8;
      int row = e >> 6, col = e & 63;
      g2l16(A + (size_t)(bm + row) * 1024 + kt + col, lA + e);
      g2l16(BT + (size_t)(bn + row) * 1024 + kt + col, lB + e);
    }
    __syncthreads();
#pragma unroll
    for (int ks = 0; ks < 2; ++ks) {
      bf16x8 af[4], bfr[4];
#pragma unroll
      for (int i = 0; i < 4; ++i)
        af[i] = *(const bf16x8*)(lA + (wr + i * 16 + lr) * 64 + ks * 32 + lk * 8);
#pragma unroll
      for (int j = 0; j < 4; ++j)
        bfr[j] = *(const bf16x8*)(lB + (wc + j * 16 + lr) * 64 + ks * 32 + lk * 8);
#pragma unroll
      for (int i = 0; i < 4; ++i)
#pragma unroll
        for (int j = 0; j < 4; ++j)
          acc[i][j] = __builtin_amdgcn_mfma_f32_16x16x32_bf16(af[i], bfr[j],
                                                              acc[i][j], 0, 0, 0);
    }
    __syncthreads();
  }
#pragma unroll
  for (int i = 0; i < 4; ++i)
#pragma unroll
    for (int j = 0; j < 4; ++j)
#pragma unroll
      for (int r = 0; r < 4; ++r) {
        int m = bm + wr + i * 16 + lk * 4 + r;
        int n = bn + wc + j * 16 + lr;
        C[(size_t)m * 1024 + n] = acc[i][j][r];
      }
}

// ---------- flash attention: 8-wave, 32x32 MFMA, swapped QK^T ----------
// Q (pre-scaled by 0.125*log2e, roped), K (roped): [b][h][l][64] bf16;
// VT: [b][h][64][l] bf16; out: [b*l][h*64] bf16.
__global__ __launch_bounds__(512, 4) void attn_k(const ushort* __restrict__ Qb,
                                                 const ushort* __restrict__ Kb,
                                                 const ushort* __restrict__ VTb,
                                                 const float* __restrict__ maskv,
                                                 ushort* __restrict__ Ob) {
  __shared__ ushort lK[2][4096];  // [key 64][d 64], 16B slot ^= row&7
  __shared__ ushort lV[2][4096];  // [d 64][key 64], 16B slot ^= row&7
  const int tid = threadIdx.x;
  const int wid = tid >> 6, lane = tid & 63;
  const int q = lane & 31, hi = lane >> 5;
  // bijective XCD swizzle: all 8 q-blocks of one bh land on one XCD
  int f = blockIdx.x;                 // 512 blocks
  int swz = (f & 7) * 64 + (f >> 3);
  int qb_i = swz & 7, bh = swz >> 3;
  int b = bh >> 4, h = bh & 15;
  const int q0w = qb_i * 256 + wid * 32;
  const ushort* qp = Qb + (size_t)bh * 2048 * 64;
  const ushort* kp = Kb + (size_t)bh * 2048 * 64;
  const ushort* vp = VTb + (size_t)bh * 64 * 2048;

  // Q B-frags: element j of step s = Q[q0w+q][16s + 8hi + j]
  bf16x8 qfr[4];
#pragma unroll
  for (int s = 0; s < 4; ++s)
    qfr[s] = *(const bf16x8*)(qp + (size_t)(q0w + q) * 64 + s * 16 + hi * 8);

  f32x16 oacc[2] = {};
  float m2 = -1e30f, ls = 0.f;

  // staging: thread t -> tile row r=t>>3, physical slot t&7, logical slot ^r&7
  const int sr = tid >> 3;
  const int ss = (tid & 7) ^ (sr & 7);
  const ushort* kg = kp + sr * 64 + ss * 8;            // + kt*4096
  const ushort* vg = vp + (size_t)sr * 2048 + ss * 8;  // + kt*64
  // read offsets: row q, slot (2j+hi)^(q&7)
  int roff[4];
#pragma unroll
  for (int j = 0; j < 4; ++j)
    roff[j] = q * 128 + (((2 * j + hi) ^ (q & 7)) << 4);

  // prologue: stage tile 0 into buf 0
  g2l16(kg, (char*)lK + tid * 16);
  g2l16(vg, (char*)lV + tid * 16);
  __syncthreads();

  int cur = 0;
  for (int kt = 0; kt < 32; ++kt) {
    // stage next tile into the dead buffer (loads fly during compute)
    if (kt < 31) {
      g2l16(kg + (kt + 1) * 4096, (char*)lK + (cur ^ 1) * 8192 + tid * 16);
      g2l16(vg + (kt + 1) * 64,   (char*)lV + (cur ^ 1) * 8192 + tid * 16);
    }
    // S^T = K @ Q^T  (Q pre-scaled)
    const char* bK = (const char*)lK + cur * 8192;
    f32x16 sacc[2] = {};
    __builtin_amdgcn_s_setprio(1);
#pragma unroll
    for (int kb2 = 0; kb2 < 2; ++kb2)
#pragma unroll
      for (int s = 0; s < 4; ++s) {
        bf16x8 kfr = *(const bf16x8*)(bK + kb2 * 4096 + roff[s]);
        sacc[kb2] = __builtin_amdgcn_mfma_f32_32x32x16_bf16(kfr, qfr[s],
                                                            sacc[kb2], 0, 0, 0);
      }
    __builtin_amdgcn_s_setprio(0);
    // + mask (log2 domain); key(reg 4g+e) = kb2*32 + 8g + 4hi + e
    const float* mbase = maskv + (size_t)b * 2048 + kt * 64;
#pragma unroll
    for (int kb2 = 0; kb2 < 2; ++kb2)
#pragma unroll
      for (int g = 0; g < 4; ++g) {
        f32x4 mv = *(const f32x4*)(mbase + kb2 * 32 + g * 8 + 4 * hi);
#pragma unroll
        for (int e = 0; e < 4; ++e) sacc[kb2][4 * g + e] += mv[e];
      }
    // online softmax with defer-max (T13): lane owns q-row
    float mx = -1e30f;
#pragma unroll
    for (int r = 0; r < 16; ++r) mx = fmaxf(mx, fmaxf(sacc[0][r], sacc[1][r]));
    mx = fmaxf(mx, __shfl_xor(mx, 32));
    const bool skip = __all(mx - m2 <= 8.f);
    float corr = 1.f;
    if (!skip) {
      float mnew = fmaxf(m2, mx);
      corr = __builtin_amdgcn_exp2f(m2 - mnew);
      m2 = mnew;
    }
    float ps = 0.f;
#pragma unroll
    for (int kb2 = 0; kb2 < 2; ++kb2)
#pragma unroll
      for (int r = 0; r < 16; ++r) {
        float p = __builtin_amdgcn_exp2f(sacc[kb2][r] - m2);
        sacc[kb2][r] = p;
        ps += p;
      }
    ps += __shfl_xor(ps, 32);
    if (skip) {
      ls += ps;
    } else {
      ls = ls * corr + ps;
#pragma unroll
      for (int d2 = 0; d2 < 2; ++d2)
#pragma unroll
        for (int r = 0; r < 16; ++r) oacc[d2][r] *= corr;
    }

    // P -> bf16 words; half-exchange via v_permlane32_swap; O^T += VT @ P^T
    const char* bV = (const char*)lV + cur * 8192;
    __builtin_amdgcn_s_setprio(1);
#pragma unroll
    for (int kb2 = 0; kb2 < 2; ++kb2) {
      unsigned w[8];
#pragma unroll
      for (int j = 0; j < 8; ++j) {
        bf16x2 t2;
        t2[0] = (bf16_t)sacc[kb2][2 * j];
        t2[1] = (bf16_t)sacc[kb2][2 * j + 1];
        w[j] = __builtin_bit_cast(unsigned, t2);
      }
#pragma unroll
      for (int sg = 0; sg < 2; ++sg) {
        // swap(a,b): a' = [a.lo|b.lo], b' = [a.hi|b.hi]  (vdst.hi <-> vsrc.lo)
        unsigned a0 = w[4 * sg + 0], b0 = w[4 * sg + 2];
        unsigned a1 = w[4 * sg + 1], b1 = w[4 * sg + 3];
        asm("v_permlane32_swap_b32 %0, %1" : "+v"(a0), "+v"(b0));
        asm("v_permlane32_swap_b32 %0, %1" : "+v"(a1), "+v"(b1));
        uint32x4 fw;
        fw[0] = a0; fw[1] = a1; fw[2] = b0; fw[3] = b1;
        bf16x8 pfr = __builtin_bit_cast(bf16x8, fw);
        int tau = kb2 * 2 + sg;
#pragma unroll
        for (int d2 = 0; d2 < 2; ++d2) {
          bf16x8 vfr = *(const bf16x8*)(bV + d2 * 4096 + roff[tau]);
          oacc[d2] = __builtin_amdgcn_mfma_f32_32x32x16_bf16(vfr, pfr,
                                                             oacc[d2], 0, 0, 0);
        }
      }
    }
    __builtin_amdgcn_s_setprio(0);
    __syncthreads();
    cur ^= 1;
  }

  // epilogue: O^T C-layout: d = d2*32 + 8g + 4hi + e, own q row
  float inv = 1.f / ls;
  const int l = q0w + q;
#pragma unroll
  for (int d2 = 0; d2 < 2; ++d2)
#pragma unroll
    for (int g = 0; g < 4; ++g) {
      ushort4 o;
      o.x = f2bu(oacc[d2][4 * g + 0] * inv);
      o.y = f2bu(oacc[d2][4 * g + 1] * inv);
      o.z = f2bu(oacc[d2][4 * g + 2] * inv);
      o.w = f2bu(oacc[d2][4 * g + 3] * inv);
      int dcol = d2 * 32 + g * 8 + 4 * hi;
      *(ushort4*)(Ob + ((size_t)b * 2048 + l) * 1024 + h * 64 + dcol) = o;
    }
}

// ---------- launch ----------
extern "C" void kernel_launch(void* const* d_in, const int* in_sizes, int n_in,
                              void* d_out, int out_size, void* d_ws, size_t ws_size,
                              hipStream_t stream) {
  const float* x  = (const float*)d_in[0];
  const float* wq = (const float*)d_in[1];
  const float* wk = (const float*)d_in[2];
  const float* wv = (const float*)d_in[3];
  const float* wo = (const float*)d_in[4];
  float* out = (float*)d_out;
  char* ws = (char*)d_ws;
  const size_t MB = 1024 * 1024;
  // layout (72 MB + 32 KB): xb aliases ao (xb dead after QKV GEMM)
  ushort* xb    = (ushort*)(ws);             // 16 MB  [8192][1024] bf16
  ushort* ao    = (ushort*)(ws);             // alias: attn out [8192][1024] bf16
  ushort* wqkvT = (ushort*)(ws + 16 * MB);   // 6 MB [3072][1024] bf16 (q,k,v)
  ushort* woT   = (ushort*)(ws + 22 * MB);   // 2 MB [1024][1024] bf16
  ushort* qb    = (ushort*)(ws + 24 * MB);   // 16 MB [b][h][l][d]
  ushort* kb    = (ushort*)(ws + 40 * MB);   // 16 MB [b][h][l][d]
  ushort* vtb   = (ushort*)(ws + 56 * MB);   // 16 MB [b][h][d][l]
  float* maskv  = (float*)(ws + 72 * MB);    // 32 KB

  pack_x<<<8192, 256, 0, stream>>>(x, xb, maskv);
  dim3 tb(32, 32);
  pack_w<<<dim3(32, 32), tb, 0, stream>>>(wq, wqkvT);
  pack_w<<<dim3(32, 32), tb, 0, stream>>>(wk, wqkvT + 1024 * 1024);
  pack_w<<<dim3(32, 32), tb, 0, stream>>>(wv, wqkvT + 2048 * 1024);
  pack_w<<<dim3(32, 32), tb, 0, stream>>>(wo, woT);
  qkv_gemm<<<1536, 256, 0, stream>>>(xb, wqkvT, qb, kb, vtb);
  attn_k<<<512, 512, 0, stream>>>(qb, kb, vtb, maskv, ao);
  wo_gemm<<<512, 256, 0, stream>>>(ao, woT, out);
}

// Round 9
// 341.994 us; speedup vs baseline: 2.3656x; 2.3656x over previous
//
#include <hip/hip_runtime.h>

// ---------- types ----------
typedef __bf16 bf16_t;
typedef bf16_t bf16x8 __attribute__((ext_vector_type(8)));
typedef bf16_t bf16x4 __attribute__((ext_vector_type(4)));
typedef bf16_t bf16x2 __attribute__((ext_vector_type(2)));
typedef float f32x4 __attribute__((ext_vector_type(4)));
typedef float f32x16 __attribute__((ext_vector_type(16)));
typedef unsigned int uint32x4 __attribute__((ext_vector_type(4)));

// ---------- helpers ----------
__device__ __forceinline__ ushort f2bu(float f) {  // fp32 -> bf16 bits (RNE)
  unsigned u = __float_as_uint(f);
  unsigned r = (u + 0x7fffu + ((u >> 16) & 1u)) >> 16;
  return (ushort)r;
}
__device__ __forceinline__ float b2f(ushort u) {
  return __uint_as_float(((unsigned)u) << 16);
}

typedef const __attribute__((address_space(1))) unsigned int* gas_ptr;
typedef __attribute__((address_space(3))) unsigned int* las_ptr;
__device__ __forceinline__ void g2l16(const void* g, void* l) {
  // async global->LDS, 16B per lane; LDS dest = wave-uniform base + lane*16
  __builtin_amdgcn_global_load_lds((gas_ptr)g, (las_ptr)l, 16, 0, 0);
}

// ---------- pack x -> bf16 + mask (mask premultiplied by log2(e)) ----------
__global__ __launch_bounds__(256) void pack_x(const float* __restrict__ x,
                                              ushort* __restrict__ xb,
                                              float* __restrict__ maskv) {
  int row = blockIdx.x;
  int tid = threadIdx.x;
  const float4 v = ((const float4*)(x + (size_t)row * 1024))[tid];
  ushort4 o;
  o.x = f2bu(v.x); o.y = f2bu(v.y); o.z = f2bu(v.z); o.w = f2bu(v.w);
  ((ushort4*)(xb + (size_t)row * 1024))[tid] = o;
  float s = v.x + v.y + v.z + v.w;
#pragma unroll
  for (int m = 1; m < 64; m <<= 1) s += __shfl_xor(s, m);
  __shared__ float wsum[4];
  if ((tid & 63) == 0) wsum[tid >> 6] = s;
  __syncthreads();
  if (tid == 0)
    maskv[row] = ((wsum[0] + wsum[1] + wsum[2] + wsum[3]) != 0.f)
                     ? 1.4426950408889634f : 0.f;
}

// ---------- pack weight: transpose + cast (wt[n][k] = w[k][n]) ----------
__global__ __launch_bounds__(1024) void pack_w(const float* __restrict__ w,
                                               ushort* __restrict__ wt) {
  __shared__ float t[32][33];
  int n0 = blockIdx.x * 32, k0 = blockIdx.y * 32;
  int tx = threadIdx.x, ty = threadIdx.y;
  t[ty][tx] = w[(size_t)(k0 + ty) * 1024 + n0 + tx];
  __syncthreads();
  wt[(size_t)(n0 + ty) * 1024 + k0 + tx] = f2bu(t[tx][ty]);
}

// ---------- GEMM: C[M,N] = A[M,K] @ BT[N,K]^T, bf16 MFMA ----------
// mode 0: bf16 out at [b][h][l][d]   (rows=(b,l), cols=(h,d); L=2048, hd=64)
// mode 1: bf16 out at [b][h][d][l]   (transposed V)
// mode 2: fp32 out, plain row-major [M][N]
__global__ __launch_bounds__(256) void gemm_bf16(const ushort* __restrict__ A,
                                                 const ushort* __restrict__ BT,
                                                 void* __restrict__ Cv,
                                                 int M, int N, int K, int mode) {
  __shared__ ushort lA[128 * 64];
  __shared__ ushort lB[128 * 64];
  const int tid = threadIdx.x;
  const int wave = tid >> 6, lane = tid & 63;
  const int lr = lane & 15, lk = lane >> 4;
  const int bm = blockIdx.x * 128, bn = blockIdx.y * 128;
  const int wr = (wave >> 1) * 64, wc = (wave & 1) * 64;
  f32x4 acc[4][4] = {};
  for (int kt = 0; kt < K; kt += 64) {
#pragma unroll
    for (int t = 0; t < 4; ++t) {
      int e = (t * 256 + tid) * 8;           // tile element idx; byte = t*4096+tid*16
      int row = e >> 6, col = e & 63;
      g2l16(A + (size_t)(bm + row) * K + kt + col, lA + e);
      g2l16(BT + (size_t)(bn + row) * K + kt + col, lB + e);
    }
    __syncthreads();
#pragma unroll
    for (int ks = 0; ks < 2; ++ks) {
      bf16x8 af[4], bfr[4];
#pragma unroll
      for (int i = 0; i < 4; ++i)
        af[i] = *(const bf16x8*)(lA + (wr + i * 16 + lr) * 64 + ks * 32 + lk * 8);
#pragma unroll
      for (int j = 0; j < 4; ++j)
        bfr[j] = *(const bf16x8*)(lB + (wc + j * 16 + lr) * 64 + ks * 32 + lk * 8);
#pragma unroll
      for (int i = 0; i < 4; ++i)
#pragma unroll
        for (int j = 0; j < 4; ++j)
          acc[i][j] = __builtin_amdgcn_mfma_f32_16x16x32_bf16(af[i], bfr[j],
                                                              acc[i][j], 0, 0, 0);
    }
    __syncthreads();
  }
  // epilogue: C/D map (verified): col = lane&15, row = (lane>>4)*4 + reg
#pragma unroll
  for (int i = 0; i < 4; ++i)
#pragma unroll
    for (int j = 0; j < 4; ++j)
#pragma unroll
      for (int r = 0; r < 4; ++r) {
        int m = bm + wr + i * 16 + lk * 4 + r;
        int n = bn + wc + j * 16 + lr;
        float v = acc[i][j][r];
        if (mode == 2) {
          ((float*)Cv)[(size_t)m * N + n] = v;
        } else {
          int b = m >> 11, l = m & 2047;
          int h = n >> 6, d = n & 63;
          size_t addr;
          if (mode == 0) addr = (((size_t)b * 16 + h) * 2048 + l) * 64 + d;
          else           addr = (((size_t)b * 16 + h) * 64 + d) * 2048 + l;
          ((ushort*)Cv)[addr] = f2bu(v);
        }
      }
}

// ---------- RoPE in place on [b][h][l][d], adjacent pairs ----------
// Q additionally pre-scaled by 0.125*log2(e) (softmax scale, log2 domain).
__global__ __launch_bounds__(256) void rope_k(ushort* __restrict__ Qb,
                                              ushort* __restrict__ Kb) {
  const size_t P1 = (size_t)64 * 2048 * 32;  // pairs per buffer
  size_t id = (size_t)blockIdx.x * 256 + threadIdx.x;
  ushort* base = Qb;
  size_t rr = id;
  bool isQ = true;
  if (id >= P1) { base = Kb; rr = id - P1; isQ = false; }
  int i = (int)(rr & 31);
  int l = (int)((rr >> 5) & 2047);
  size_t bh = rr >> 16;
  size_t addr = (bh * 2048 + (size_t)l) * 64 + 2 * i;
  unsigned p = *(const unsigned*)(base + addr);
  float x1 = b2f((ushort)(p & 0xffffu));
  float x2 = b2f((ushort)(p >> 16));
  const float c = 0.41524101186092029f;  // log2(10000)/32
  float inv = exp2f(-c * (float)i);
  float ang = (float)l * inv;
  float sv, cv;
  sincosf(ang, &sv, &cv);
  float r1 = x1 * cv - x2 * sv;
  float r2 = x1 * sv + x2 * cv;
  if (isQ) {
    const float SCL = 0.18033688011112042f;  // 0.125 * log2(e)
    r1 *= SCL; r2 *= SCL;
  }
  unsigned o = (unsigned)f2bu(r1) | ((unsigned)f2bu(r2) << 16);
  *(unsigned*)(base + addr) = o;
}

// ---------- flash attention: 8-wave, 32x32 MFMA, swapped QK^T ----------
// Q (pre-scaled by 0.125*log2e, roped), K (roped): [b][h][l][64] bf16;
// VT: [b][h][64][l] bf16; out: [b*l][h*64] bf16.
__global__ __launch_bounds__(512, 4) void attn_k(const ushort* __restrict__ Qb,
                                                 const ushort* __restrict__ Kb,
                                                 const ushort* __restrict__ VTb,
                                                 const float* __restrict__ maskv,
                                                 ushort* __restrict__ Ob) {
  __shared__ ushort lK[2][4096];  // [key 64][d 64], 16B slot ^= row&7
  __shared__ ushort lV[2][4096];  // [d 64][key 64], 16B slot ^= row&7
  const int tid = threadIdx.x;
  const int wid = tid >> 6, lane = tid & 63;
  const int q = lane & 31, hi = lane >> 5;
  // bijective XCD swizzle: all 8 q-blocks of one bh land on one XCD
  int f = blockIdx.x;                 // 512 blocks
  int swz = (f & 7) * 64 + (f >> 3);
  int qb_i = swz & 7, bh = swz >> 3;
  int b = bh >> 4, h = bh & 15;
  const int q0w = qb_i * 256 + wid * 32;
  const ushort* qp = Qb + (size_t)bh * 2048 * 64;
  const ushort* kp = Kb + (size_t)bh * 2048 * 64;
  const ushort* vp = VTb + (size_t)bh * 64 * 2048;

  // Q B-frags: element j of step s = Q[q0w+q][16s + 8hi + j]
  bf16x8 qfr[4];
#pragma unroll
  for (int s = 0; s < 4; ++s)
    qfr[s] = *(const bf16x8*)(qp + (size_t)(q0w + q) * 64 + s * 16 + hi * 8);

  f32x16 oacc[2] = {};
  float m2 = -1e30f, ls = 0.f;

  // staging: thread t -> tile row r=t>>3, physical slot t&7, logical slot ^r&7
  const int sr = tid >> 3;
  const int ss = (tid & 7) ^ (sr & 7);
  const ushort* kg = kp + sr * 64 + ss * 8;            // + kt*4096
  const ushort* vg = vp + (size_t)sr * 2048 + ss * 8;  // + kt*64
  // read offsets: row q, slot (2j+hi)^(q&7)
  int roff[4];
#pragma unroll
  for (int j = 0; j < 4; ++j)
    roff[j] = q * 128 + (((2 * j + hi) ^ (q & 7)) << 4);

  // prologue: stage tile 0 into buf 0
  g2l16(kg, (char*)lK + tid * 16);
  g2l16(vg, (char*)lV + tid * 16);
  __syncthreads();

  int cur = 0;
  for (int kt = 0; kt < 32; ++kt) {
    // stage next tile into the dead buffer (loads fly during compute)
    if (kt < 31) {
      g2l16(kg + (kt + 1) * 4096, (char*)lK + (cur ^ 1) * 8192 + tid * 16);
      g2l16(vg + (kt + 1) * 64,   (char*)lV + (cur ^ 1) * 8192 + tid * 16);
    }
    // S^T = K @ Q^T  (Q pre-scaled)
    const char* bK = (const char*)lK + cur * 8192;
    f32x16 sacc[2] = {};
    __builtin_amdgcn_s_setprio(1);
#pragma unroll
    for (int kb2 = 0; kb2 < 2; ++kb2)
#pragma unroll
      for (int s = 0; s < 4; ++s) {
        bf16x8 kfr = *(const bf16x8*)(bK + kb2 * 4096 + roff[s]);
        sacc[kb2] = __builtin_amdgcn_mfma_f32_32x32x16_bf16(kfr, qfr[s],
                                                            sacc[kb2], 0, 0, 0);
      }
    __builtin_amdgcn_s_setprio(0);
    // + mask (log2 domain); key(reg 4g+e) = kb2*32 + 8g + 4hi + e
    const float* mbase = maskv + (size_t)b * 2048 + kt * 64;
#pragma unroll
    for (int kb2 = 0; kb2 < 2; ++kb2)
#pragma unroll
      for (int g = 0; g < 4; ++g) {
        f32x4 mv = *(const f32x4*)(mbase + kb2 * 32 + g * 8 + 4 * hi);
#pragma unroll
        for (int e = 0; e < 4; ++e) sacc[kb2][4 * g + e] += mv[e];
      }
    // online softmax with defer-max (T13): lane owns q-row
    float mx = -1e30f;
#pragma unroll
    for (int r = 0; r < 16; ++r) mx = fmaxf(mx, fmaxf(sacc[0][r], sacc[1][r]));
    mx = fmaxf(mx, __shfl_xor(mx, 32));
    const bool skip = __all(mx - m2 <= 8.f);
    float corr = 1.f;
    if (!skip) {
      float mnew = fmaxf(m2, mx);
      corr = __builtin_amdgcn_exp2f(m2 - mnew);
      m2 = mnew;
    }
    float ps = 0.f;
#pragma unroll
    for (int kb2 = 0; kb2 < 2; ++kb2)
#pragma unroll
      for (int r = 0; r < 16; ++r) {
        float p = __builtin_amdgcn_exp2f(sacc[kb2][r] - m2);
        sacc[kb2][r] = p;
        ps += p;
      }
    ps += __shfl_xor(ps, 32);
    if (skip) {
      ls += ps;
    } else {
      ls = ls * corr + ps;
#pragma unroll
      for (int d2 = 0; d2 < 2; ++d2)
#pragma unroll
        for (int r = 0; r < 16; ++r) oacc[d2][r] *= corr;
    }

    // P -> bf16 words; half-exchange via v_permlane32_swap; O^T += VT @ P^T
    const char* bV = (const char*)lV + cur * 8192;
    __builtin_amdgcn_s_setprio(1);
#pragma unroll
    for (int kb2 = 0; kb2 < 2; ++kb2) {
      unsigned w[8];
#pragma unroll
      for (int j = 0; j < 8; ++j) {
        bf16x2 t2;
        t2[0] = (bf16_t)sacc[kb2][2 * j];
        t2[1] = (bf16_t)sacc[kb2][2 * j + 1];
        w[j] = __builtin_bit_cast(unsigned, t2);
      }
#pragma unroll
      for (int sg = 0; sg < 2; ++sg) {
        // swap(a,b): a' = [a.lo|b.lo], b' = [a.hi|b.hi]  (vdst.hi <-> vsrc.lo)
        unsigned a0 = w[4 * sg + 0], b0 = w[4 * sg + 2];
        unsigned a1 = w[4 * sg + 1], b1 = w[4 * sg + 3];
        asm("v_permlane32_swap_b32 %0, %1" : "+v"(a0), "+v"(b0));
        asm("v_permlane32_swap_b32 %0, %1" : "+v"(a1), "+v"(b1));
        uint32x4 fw;
        fw[0] = a0; fw[1] = a1; fw[2] = b0; fw[3] = b1;
        bf16x8 pfr = __builtin_bit_cast(bf16x8, fw);
        int tau = kb2 * 2 + sg;
#pragma unroll
        for (int d2 = 0; d2 < 2; ++d2) {
          bf16x8 vfr = *(const bf16x8*)(bV + d2 * 4096 + roff[tau]);
          oacc[d2] = __builtin_amdgcn_mfma_f32_32x32x16_bf16(vfr, pfr,
                                                             oacc[d2], 0, 0, 0);
        }
      }
    }
    __builtin_amdgcn_s_setprio(0);
    __syncthreads();
    cur ^= 1;
  }

  // epilogue: O^T C-layout: d = d2*32 + 8g + 4hi + e, own q row
  float inv = 1.f / ls;
  const int l = q0w + q;
#pragma unroll
  for (int d2 = 0; d2 < 2; ++d2)
#pragma unroll
    for (int g = 0; g < 4; ++g) {
      ushort4 o;
      o.x = f2bu(oacc[d2][4 * g + 0] * inv);
      o.y = f2bu(oacc[d2][4 * g + 1] * inv);
      o.z = f2bu(oacc[d2][4 * g + 2] * inv);
      o.w = f2bu(oacc[d2][4 * g + 3] * inv);
      int dcol = d2 * 32 + g * 8 + 4 * hi;
      *(ushort4*)(Ob + ((size_t)b * 2048 + l) * 1024 + h * 64 + dcol) = o;
    }
}

// ---------- launch ----------
extern "C" void kernel_launch(void* const* d_in, const int* in_sizes, int n_in,
                              void* d_out, int out_size, void* d_ws, size_t ws_size,
                              hipStream_t stream) {
  const float* x  = (const float*)d_in[0];
  const float* wq = (const float*)d_in[1];
  const float* wk = (const float*)d_in[2];
  const float* wv = (const float*)d_in[3];
  const float* wo = (const float*)d_in[4];
  float* out = (float*)d_out;
  char* ws = (char*)d_ws;
  const size_t MB = 1024 * 1024;
  // layout (72 MB + 32 KB): xb aliases ao (xb dead after QKV GEMMs)
  ushort* xb   = (ushort*)(ws);             // 16 MB  [8192][1024] bf16
  ushort* ao   = (ushort*)(ws);             // alias: attn out [8192][1024] bf16
  ushort* wqT  = (ushort*)(ws + 16 * MB);   // 2 MB each, [N][K] bf16
  ushort* wkT  = (ushort*)(ws + 18 * MB);
  ushort* wvT  = (ushort*)(ws + 20 * MB);
  ushort* woT  = (ushort*)(ws + 22 * MB);
  ushort* qb   = (ushort*)(ws + 24 * MB);   // 16 MB [b][h][l][d]
  ushort* kb   = (ushort*)(ws + 40 * MB);   // 16 MB [b][h][l][d]
  ushort* vtb  = (ushort*)(ws + 56 * MB);   // 16 MB [b][h][d][l]
  float* maskv = (float*)(ws + 72 * MB);    // 32 KB

  pack_x<<<8192, 256, 0, stream>>>(x, xb, maskv);
  dim3 tb(32, 32);
  pack_w<<<dim3(32, 32), tb, 0, stream>>>(wq, wqT);
  pack_w<<<dim3(32, 32), tb, 0, stream>>>(wk, wkT);
  pack_w<<<dim3(32, 32), tb, 0, stream>>>(wv, wvT);
  pack_w<<<dim3(32, 32), tb, 0, stream>>>(wo, woT);
  gemm_bf16<<<dim3(64, 8), 256, 0, stream>>>(xb, wqT, qb, 8192, 1024, 1024, 0);
  gemm_bf16<<<dim3(64, 8), 256, 0, stream>>>(xb, wkT, kb, 8192, 1024, 1024, 0);
  gemm_bf16<<<dim3(64, 8), 256, 0, stream>>>(xb, wvT, vtb, 8192, 1024, 1024, 1);
  rope_k<<<32768, 256, 0, stream>>>(qb, kb);
  attn_k<<<512, 512, 0, stream>>>(qb, kb, vtb, maskv, ao);
  gemm_bf16<<<dim3(64, 8), 256, 0, stream>>>(ao, woT, out, 8192, 1024, 1024, 2);
}